// Round 3
// baseline (236.448 us; speedup 1.0000x reference)
//
#include <hip/hip_runtime.h>

// B=32, C=64, H=128, W=128, N_KNOTS=65. x is (B,C,H,W) row-major, 33,554,432 floats.
// Thread handles FOUR vec4s (64 B); 256-thread block covers 4096 contiguous floats
// = 1/4 of one (b,c) channel slice, so the whole block shares ONE channel's table.
//
// R3 experiment: ONLY change vs R2 = drop nontemporal hints (plain cached
// loads/stores). Theory: nt bypasses LLC allocation; regular stores get L3
// write-combining (the 6.7 TB/s harness fills use regular stores), nt stores
// drive HBM turnaround synchronously. Everything else byte-identical.
//
// LDS holds PRECOMPUTED per-interval polynomial coefficients:
//   out = a0 + a1*s + a2*s^2
//   a0 = (c0+c1)/2,  a1 = c1-c0,  a2 = (c0-2*c1+c2)/2
// One aligned ds_read_b128 per element; idx Gaussian mod 8 -> uniform banks.
//
// Math equivalence with reference (established in prior rounds):
//   t  = x * inv_g            (exact: g = 2^-3, inv_g = 8)
//   fl = clamp(floor(t), -32, 30) == floor(clamp(x)/g)
//   s  = t - fl               == (x - fl*g)/g   (identical rounding)

typedef float vfloat4 __attribute__((ext_vector_type(4)));

__global__ __launch_bounds__(256) void quad_spline_kernel(
    const vfloat4* __restrict__ x,
    const float*   __restrict__ coeffs,
    const float*   __restrict__ grid_p,
    const int*     __restrict__ zki,
    const int*     __restrict__ size_p,
    vfloat4*       __restrict__ out)
{
    __shared__ vfloat4 lds_a[63];   // (a0, a1, a2, pad) per interval, idx in [0,62]

    const int tid   = threadIdx.x;
    const int vbase = blockIdx.x * 1024 + tid;  // 1024 vec4 per block
    const int c     = (blockIdx.x >> 2) & 63;   // 4 blocks per (b,c) slice

    // Issue all streaming loads FIRST so HBM latency overlaps staging + sync.
    vfloat4 x0 = x[vbase];
    vfloat4 x1 = x[vbase + 256];
    vfloat4 x2 = x[vbase + 512];
    vfloat4 x3 = x[vbase + 768];

    const float g    = grid_p[0];
    const int   size = size_p[0];
    const int   half = size >> 1;               // 32
    const int   base = zki[c] - half;           // = c * size

    if (tid < 63) {
        float c0 = coeffs[base + tid];
        float c1 = coeffs[base + tid + 1];
        float c2 = coeffs[base + tid + 2];
        vfloat4 a;
        a.x = 0.5f * (c0 + c1);                 // a0
        a.y = c1 - c0;                          // a1
        a.z = 0.5f * ((c0 - c1) + (c2 - c1));   // a2
        a.w = 0.0f;
        lds_a[tid] = a;
    }
    __syncthreads();

    const float inv_g = 1.0f / g;               // exact (g = 0.125)
    const float flo   = -(float)half;           // -32
    const float fhi   =  (float)(half - 2);     //  30

    #define SPLINE(xx, dst)                                            \
    {                                                                  \
        float t   = (xx) * inv_g;                                      \
        float fl  = fminf(fmaxf(floorf(t), flo), fhi);                 \
        int   idx = half + (int)fl;                                    \
        float s   = t - fl;                                            \
        vfloat4 a = lds_a[idx];                                        \
        (dst) = fmaf(s, fmaf(s, a.z, a.y), a.x);                       \
    }

    vfloat4 r0, r1, r2, r3;
    SPLINE(x0.x, r0.x) SPLINE(x0.y, r0.y) SPLINE(x0.z, r0.z) SPLINE(x0.w, r0.w)
    SPLINE(x1.x, r1.x) SPLINE(x1.y, r1.y) SPLINE(x1.z, r1.z) SPLINE(x1.w, r1.w)
    SPLINE(x2.x, r2.x) SPLINE(x2.y, r2.y) SPLINE(x2.z, r2.z) SPLINE(x2.w, r2.w)
    SPLINE(x3.x, r3.x) SPLINE(x3.y, r3.y) SPLINE(x3.z, r3.z) SPLINE(x3.w, r3.w)
    #undef SPLINE

    out[vbase]       = r0;
    out[vbase + 256] = r1;
    out[vbase + 512] = r2;
    out[vbase + 768] = r3;
}

extern "C" void kernel_launch(void* const* d_in, const int* in_sizes, int n_in,
                              void* d_out, int out_size, void* d_ws, size_t ws_size,
                              hipStream_t stream) {
    const vfloat4* x      = (const vfloat4*)d_in[0];
    const float*   coeffs = (const float*)d_in[1];
    const float*   grid_p = (const float*)d_in[2];
    const int*     zki    = (const int*)d_in[3];
    const int*     size_p = (const int*)d_in[4];
    vfloat4*       out    = (vfloat4*)d_out;

    const int n4     = in_sizes[0] / 4;   // 8,388,608 vec4
    const int blocks = n4 / 1024;         // 8192 blocks, 4 vec4 per thread

    quad_spline_kernel<<<blocks, 256, 0, stream>>>(x, coeffs, grid_p, zki, size_p, out);
}

// Round 4
// 230.387 us; speedup vs baseline: 1.0263x; 1.0263x over previous
//
#include <hip/hip_runtime.h>

// B=32, C=64, H=128, W=128, N_KNOTS=65. x is (B,C,H,W) row-major, 33,554,432 floats.
// R4 structure: ONE block per (b,c) slice. 2048 blocks x 256 threads; each thread
// handles 16 vec4 (4 chunks of 4) from a single channel slice (16384 floats).
//  - staging + __syncthreads once per 4096 vec4 (4x fewer than R2)
//  - streaming x-loads issued AFTER the barrier, so the barrier's vmcnt(0) drain
//    never touches them (only the 3 tiny coeff gathers + LDS writes)
//  - depth-2 ping-pong pipeline (a/b static register sets): chunk k+1 loads issue
//    while chunk k computes, each load covered by ~1 chunk of VALU+LDS work
//  - nt loads/stores restored (R3 A/B showed dropping them costs +12 us)
//
// LDS holds PRECOMPUTED per-interval polynomial coefficients:
//   out = a0 + a1*s + a2*s^2
//   a0 = (c0+c1)/2,  a1 = c1-c0,  a2 = (c0-2*c1+c2)/2
// One aligned ds_read_b128 per element; idx Gaussian mod 8 -> uniform banks.
//
// Math equivalence with reference (established in prior rounds):
//   t  = x * inv_g            (exact: g = 2^-3, inv_g = 8)
//   fl = clamp(floor(t), -32, 30) == floor(clamp(x)/g)
//   s  = t - fl               == (x - fl*g)/g   (identical rounding)

typedef float vfloat4 __attribute__((ext_vector_type(4)));

__global__ __launch_bounds__(256) void quad_spline_kernel(
    const vfloat4* __restrict__ x,
    const float*   __restrict__ coeffs,
    const float*   __restrict__ grid_p,
    const int*     __restrict__ zki,
    const int*     __restrict__ size_p,
    vfloat4*       __restrict__ out)
{
    __shared__ vfloat4 lds_a[63];   // (a0, a1, a2, pad) per interval, idx in [0,62]

    const int tid   = threadIdx.x;
    const int slice = blockIdx.x;              // b*64 + c
    const int c     = slice & 63;
    const int vbase = slice * 4096 + tid;      // 4096 vec4 per slice

    const float g    = grid_p[0];
    const int   size = size_p[0];
    const int   half = size >> 1;              // 32
    const int   base = zki[c] - half;          // = c * size

    if (tid < 63) {
        float c0 = coeffs[base + tid];
        float c1 = coeffs[base + tid + 1];
        float c2 = coeffs[base + tid + 2];
        vfloat4 a;
        a.x = 0.5f * (c0 + c1);                // a0
        a.y = c1 - c0;                         // a1
        a.z = 0.5f * ((c0 - c1) + (c2 - c1));  // a2
        a.w = 0.0f;
        lds_a[tid] = a;
    }
    __syncthreads();   // drains only staging loads + LDS writes; x loads not yet issued

    const float inv_g = 1.0f / g;              // exact (g = 0.125)
    const float flo   = -(float)half;          // -32
    const float fhi   =  (float)(half - 2);    //  30

    #define SPLINE(xx, dst)                                            \
    {                                                                  \
        float t   = (xx) * inv_g;                                      \
        float fl  = fminf(fmaxf(floorf(t), flo), fhi);                 \
        int   idx = half + (int)fl;                                    \
        float s   = t - fl;                                            \
        vfloat4 a = lds_a[idx];                                        \
        (dst) = fmaf(s, fmaf(s, a.z, a.y), a.x);                       \
    }

    #define COMPUTE4(xv0, xv1, xv2, xv3, off)                          \
    {                                                                  \
        vfloat4 r0, r1, r2, r3;                                        \
        SPLINE(xv0.x, r0.x) SPLINE(xv0.y, r0.y)                        \
        SPLINE(xv0.z, r0.z) SPLINE(xv0.w, r0.w)                        \
        SPLINE(xv1.x, r1.x) SPLINE(xv1.y, r1.y)                        \
        SPLINE(xv1.z, r1.z) SPLINE(xv1.w, r1.w)                        \
        SPLINE(xv2.x, r2.x) SPLINE(xv2.y, r2.y)                        \
        SPLINE(xv2.z, r2.z) SPLINE(xv2.w, r2.w)                        \
        SPLINE(xv3.x, r3.x) SPLINE(xv3.y, r3.y)                        \
        SPLINE(xv3.z, r3.z) SPLINE(xv3.w, r3.w)                        \
        __builtin_nontemporal_store(r0, &out[(off)]);                  \
        __builtin_nontemporal_store(r1, &out[(off) + 256]);            \
        __builtin_nontemporal_store(r2, &out[(off) + 512]);            \
        __builtin_nontemporal_store(r3, &out[(off) + 768]);            \
    }

    // ---- depth-2 ping-pong pipeline over 4 chunks of 1024 vec4 ----
    // prologue: chunk0 -> A, chunk1 -> B
    vfloat4 xa0 = __builtin_nontemporal_load(&x[vbase]);
    vfloat4 xa1 = __builtin_nontemporal_load(&x[vbase + 256]);
    vfloat4 xa2 = __builtin_nontemporal_load(&x[vbase + 512]);
    vfloat4 xa3 = __builtin_nontemporal_load(&x[vbase + 768]);

    vfloat4 xb0 = __builtin_nontemporal_load(&x[vbase + 1024]);
    vfloat4 xb1 = __builtin_nontemporal_load(&x[vbase + 1280]);
    vfloat4 xb2 = __builtin_nontemporal_load(&x[vbase + 1536]);
    vfloat4 xb3 = __builtin_nontemporal_load(&x[vbase + 1792]);

    // chunk0 compute (A), then refill A with chunk2
    COMPUTE4(xa0, xa1, xa2, xa3, vbase);
    xa0 = __builtin_nontemporal_load(&x[vbase + 2048]);
    xa1 = __builtin_nontemporal_load(&x[vbase + 2304]);
    xa2 = __builtin_nontemporal_load(&x[vbase + 2560]);
    xa3 = __builtin_nontemporal_load(&x[vbase + 2816]);

    // chunk1 compute (B), then refill B with chunk3
    COMPUTE4(xb0, xb1, xb2, xb3, vbase + 1024);
    xb0 = __builtin_nontemporal_load(&x[vbase + 3072]);
    xb1 = __builtin_nontemporal_load(&x[vbase + 3328]);
    xb2 = __builtin_nontemporal_load(&x[vbase + 3584]);
    xb3 = __builtin_nontemporal_load(&x[vbase + 3840]);

    // chunk2 compute (A)
    COMPUTE4(xa0, xa1, xa2, xa3, vbase + 2048);
    // chunk3 compute (B)
    COMPUTE4(xb0, xb1, xb2, xb3, vbase + 3072);

    #undef COMPUTE4
    #undef SPLINE
}

extern "C" void kernel_launch(void* const* d_in, const int* in_sizes, int n_in,
                              void* d_out, int out_size, void* d_ws, size_t ws_size,
                              hipStream_t stream) {
    const vfloat4* x      = (const vfloat4*)d_in[0];
    const float*   coeffs = (const float*)d_in[1];
    const float*   grid_p = (const float*)d_in[2];
    const int*     zki    = (const int*)d_in[3];
    const int*     size_p = (const int*)d_in[4];
    vfloat4*       out    = (vfloat4*)d_out;

    const int n4     = in_sizes[0] / 4;   // 8,388,608 vec4
    const int blocks = n4 / 4096;         // 2048 blocks = one per (b,c) slice

    quad_spline_kernel<<<blocks, 256, 0, stream>>>(x, coeffs, grid_p, zki, size_p, out);
}